// Round 3
// baseline (226.450 us; speedup 1.0000x reference)
//
#include <hip/hip_runtime.h>
#include <hip/hip_bf16.h>

using bf16x8 = __attribute__((ext_vector_type(8))) __bf16;
using f32x4  = __attribute__((ext_vector_type(4))) float;
using i32x4  = __attribute__((ext_vector_type(4))) int;

#define MFMA_16x16x32(a, b, c) __builtin_amdgcn_mfma_f32_16x16x32_bf16((a), (b), (c), 0, 0, 0)

__device__ __forceinline__ ushort f2bf(float f) {
    return __builtin_bit_cast(ushort, (__bf16)f);
}

// ---------------------------------------------------------------------------
// QKV GEMM: C[M, 512] = A[M,512](fp32) * W[512,512](fp32)^T * scale
// out -> bf16 head-interleaved [b,h,t,64]  (b local to launch: row>>11)
// tile 128x128, BK=32, 4 waves x (64x64 = 4x4 MFMA frags)
// ---------------------------------------------------------------------------
__global__ __launch_bounds__(256) void gemm_qkv(
    const float* __restrict__ A, const float* __restrict__ W,
    float scale, ushort* __restrict__ out)
{
    __shared__ ushort lA[128][40];
    __shared__ ushort lB[128][40];
    const int m0 = blockIdx.x * 128;
    const int n0 = blockIdx.y * 128;
    const int tid  = threadIdx.x;
    const int lane = tid & 63;
    const int wave = tid >> 6;
    const int wr = (wave >> 1) * 64, wc = (wave & 1) * 64;
    const int frow = lane & 15, fk = (lane >> 4) * 8;
    const int sr = tid >> 1, scc = (tid & 1) * 16;

    f32x4 acc[4][4] = {};

    for (int k0 = 0; k0 < 512; k0 += 32) {
        const float* pa = A + (m0 + sr) * 512 + k0 + scc;
        const f32x4 a0 = *(const f32x4*)(pa);
        const f32x4 a1 = *(const f32x4*)(pa + 4);
        const f32x4 a2 = *(const f32x4*)(pa + 8);
        const f32x4 a3 = *(const f32x4*)(pa + 12);
        const float* pb = W + (n0 + sr) * 512 + k0 + scc;
        const f32x4 b0 = *(const f32x4*)(pb);
        const f32x4 b1 = *(const f32x4*)(pb + 4);
        const f32x4 b2 = *(const f32x4*)(pb + 8);
        const f32x4 b3 = *(const f32x4*)(pb + 12);
        union { ushort u[16]; i32x4 w[2]; } pA, pB;
        #pragma unroll
        for (int j = 0; j < 4; ++j) {
            pA.u[j]      = f2bf(a0[j]);  pA.u[4 + j]  = f2bf(a1[j]);
            pA.u[8 + j]  = f2bf(a2[j]);  pA.u[12 + j] = f2bf(a3[j]);
            pB.u[j]      = f2bf(b0[j]);  pB.u[4 + j]  = f2bf(b1[j]);
            pB.u[8 + j]  = f2bf(b2[j]);  pB.u[12 + j] = f2bf(b3[j]);
        }
        __syncthreads();                       // prior iter's LDS reads done
        *(i32x4*)&lA[sr][scc]     = pA.w[0];
        *(i32x4*)&lA[sr][scc + 8] = pA.w[1];
        *(i32x4*)&lB[sr][scc]     = pB.w[0];
        *(i32x4*)&lB[sr][scc + 8] = pB.w[1];
        __syncthreads();

        bf16x8 af[4], bg[4];
        #pragma unroll
        for (int m = 0; m < 4; ++m) af[m] = *(const bf16x8*)&lA[wr + m * 16 + frow][fk];
        #pragma unroll
        for (int n = 0; n < 4; ++n) bg[n] = *(const bf16x8*)&lB[wc + n * 16 + frow][fk];
        #pragma unroll
        for (int m = 0; m < 4; ++m)
            #pragma unroll
            for (int n = 0; n < 4; ++n)
                acc[m][n] = MFMA_16x16x32(af[m], bg[n], acc[m][n]);
    }

    const int rbase = (lane >> 4) * 4;
    const int ccol  = lane & 15;
    #pragma unroll
    for (int m = 0; m < 4; ++m)
        #pragma unroll
        for (int n = 0; n < 4; ++n) {
            const int col = n0 + wc + n * 16 + ccol;
            #pragma unroll
            for (int r = 0; r < 4; ++r) {
                const int row = m0 + wr + m * 16 + rbase + r;
                out[(((row >> 11) * 8 + (col >> 6)) * 2048 + (row & 2047)) * 64 + (col & 63)]
                    = f2bf(acc[m][n][r] * scale);
            }
        }
}

// ---------------------------------------------------------------------------
// Output GEMM: C[M,512](fp32) = A[M,512](bf16, head-interleaved) * Wp^T + bp
// ---------------------------------------------------------------------------
__global__ __launch_bounds__(256) void gemm_out(
    const ushort* __restrict__ A, const float* __restrict__ W,
    const float* __restrict__ bias, float* __restrict__ out)
{
    __shared__ ushort lA[128][40];
    __shared__ ushort lB[128][40];
    const int m0 = blockIdx.x * 128;
    const int n0 = blockIdx.y * 128;
    const int tid  = threadIdx.x;
    const int lane = tid & 63;
    const int wave = tid >> 6;
    const int wr = (wave >> 1) * 64, wc = (wave & 1) * 64;
    const int frow = lane & 15, fk = (lane >> 4) * 8;
    const int sr = tid >> 1, scc = (tid & 1) * 16;

    f32x4 acc[4][4] = {};

    for (int k0 = 0; k0 < 512; k0 += 32) {
        const int row = m0 + sr, c = k0 + scc;
        const ushort* pa = A + ((((row >> 11) * 8 + (c >> 6)) * 2048 + (row & 2047)) * 64 + (c & 63));
        const i32x4 va0 = *(const i32x4*)(pa);
        const i32x4 va1 = *(const i32x4*)(pa + 8);
        const float* pb = W + (n0 + sr) * 512 + k0 + scc;
        const f32x4 b0 = *(const f32x4*)(pb);
        const f32x4 b1 = *(const f32x4*)(pb + 4);
        const f32x4 b2 = *(const f32x4*)(pb + 8);
        const f32x4 b3 = *(const f32x4*)(pb + 12);
        union { ushort u[16]; i32x4 w[2]; } pB;
        #pragma unroll
        for (int j = 0; j < 4; ++j) {
            pB.u[j]      = f2bf(b0[j]);  pB.u[4 + j]  = f2bf(b1[j]);
            pB.u[8 + j]  = f2bf(b2[j]);  pB.u[12 + j] = f2bf(b3[j]);
        }
        __syncthreads();
        *(i32x4*)&lA[sr][scc]     = va0;
        *(i32x4*)&lA[sr][scc + 8] = va1;
        *(i32x4*)&lB[sr][scc]     = pB.w[0];
        *(i32x4*)&lB[sr][scc + 8] = pB.w[1];
        __syncthreads();

        bf16x8 af[4], bg[4];
        #pragma unroll
        for (int m = 0; m < 4; ++m) af[m] = *(const bf16x8*)&lA[wr + m * 16 + frow][fk];
        #pragma unroll
        for (int n = 0; n < 4; ++n) bg[n] = *(const bf16x8*)&lB[wc + n * 16 + frow][fk];
        #pragma unroll
        for (int m = 0; m < 4; ++m)
            #pragma unroll
            for (int n = 0; n < 4; ++n)
                acc[m][n] = MFMA_16x16x32(af[m], bg[n], acc[m][n]);
    }

    const int rbase = (lane >> 4) * 4;
    const int ccol  = lane & 15;
    #pragma unroll
    for (int m = 0; m < 4; ++m)
        #pragma unroll
        for (int n = 0; n < 4; ++n) {
            const int col = n0 + wc + n * 16 + ccol;
            const float bv = bias[col];
            #pragma unroll
            for (int r = 0; r < 4; ++r) {
                const int row = m0 + wr + m * 16 + rbase + r;
                out[row * 512 + col] = acc[m][n][r] + bv;
            }
        }
}

// ---------------------------------------------------------------------------
// Causal flash attention per (local bh): Q,K,V [2048,64] bf16 (q pre-scaled).
// Block: 128 q-rows, 4 waves x 32 rows. KV tiles of 64 staged in LDS.
// ---------------------------------------------------------------------------
__global__ __launch_bounds__(256) void attn_kernel(
    const ushort* __restrict__ q, const ushort* __restrict__ k,
    const ushort* __restrict__ v, ushort* __restrict__ att)
{
    __shared__ ushort lK[64][72];       // K tile row-major [s][d]
    __shared__ ushort lV[64][72];       // V tile transposed [d][s]
    __shared__ ushort lP[4][32][72];    // per-wave P round-trip

    const int bh  = blockIdx.y;
    const int qt0 = blockIdx.x * 128;
    const ushort* Q = q + bh * 2048 * 64;
    const ushort* K = k + bh * 2048 * 64;
    const ushort* V = v + bh * 2048 * 64;
    ushort* O = att + bh * 2048 * 64;

    const int tid = threadIdx.x, wave = tid >> 6, lane = tid & 63;
    const int wrow = wave * 32;
    const int frow = lane & 15, fk8 = (lane >> 4) * 8;
    const int rbase = (lane >> 4) * 4;
    const float LOG2E = 1.44269504088896f;
    const float NEG = -30000.0f;        // bf16-safe "minus infinity"

    bf16x8 aq[2][2];
    #pragma unroll
    for (int m = 0; m < 2; ++m)
        #pragma unroll
        for (int ks = 0; ks < 2; ++ks)
            aq[m][ks] = *(const bf16x8*)(Q + (qt0 + wrow + m * 16 + frow) * 64 + ks * 32 + fk8);

    f32x4 o[2][4] = {};
    float mrun[2][4], lrun[2][4];
    #pragma unroll
    for (int m = 0; m < 2; ++m)
        #pragma unroll
        for (int r = 0; r < 4; ++r) { mrun[m][r] = NEG; lrun[m][r] = 0.f; }

    const int ls = tid >> 2, cq = (tid & 3) * 16;
    const int send = qt0 + 128;          // causal: no tiles beyond the q-tile

    for (int s0 = 0; s0 < send; s0 += 64) {
        const i32x4 kx0 = *(const i32x4*)(K + (s0 + ls) * 64 + cq);
        const i32x4 kx1 = *(const i32x4*)(K + (s0 + ls) * 64 + cq + 8);
        const i32x4 vv0 = *(const i32x4*)(V + (s0 + ls) * 64 + cq);
        const i32x4 vv1 = *(const i32x4*)(V + (s0 + ls) * 64 + cq + 8);
        __syncthreads();
        *(i32x4*)&lK[ls][cq]     = kx0;
        *(i32x4*)&lK[ls][cq + 8] = kx1;
        #pragma unroll
        for (int j = 0; j < 4; ++j) {
            lV[cq + 2 * j][ls]         = (ushort)(((unsigned)vv0[j]) & 0xffffu);
            lV[cq + 2 * j + 1][ls]     = (ushort)(((unsigned)vv0[j]) >> 16);
            lV[cq + 8 + 2 * j][ls]     = (ushort)(((unsigned)vv1[j]) & 0xffffu);
            lV[cq + 8 + 2 * j + 1][ls] = (ushort)(((unsigned)vv1[j]) >> 16);
        }
        __syncthreads();

        f32x4 s[2][4] = {};
        #pragma unroll
        for (int sf = 0; sf < 4; ++sf) {
            #pragma unroll
            for (int ks = 0; ks < 2; ++ks) {
                const bf16x8 kb = *(const bf16x8*)&lK[sf * 16 + frow][ks * 32 + fk8];
                #pragma unroll
                for (int m = 0; m < 2; ++m)
                    s[m][sf] = MFMA_16x16x32(aq[m][ks], kb, s[m][sf]);
            }
        }
        if (s0 + 63 > qt0 + wrow) {
            #pragma unroll
            for (int m = 0; m < 2; ++m)
                #pragma unroll
                for (int sf = 0; sf < 4; ++sf)
                    #pragma unroll
                    for (int r = 0; r < 4; ++r) {
                        const int row = qt0 + wrow + m * 16 + rbase + r;
                        const int col = s0 + sf * 16 + (lane & 15);
                        if (col > row) s[m][sf][r] = NEG;
                    }
        }
        #pragma unroll
        for (int m = 0; m < 2; ++m) {
            float pmax[4], alpha[4], psum[4];
            #pragma unroll
            for (int r = 0; r < 4; ++r)
                pmax[r] = fmaxf(fmaxf(s[m][0][r], s[m][1][r]), fmaxf(s[m][2][r], s[m][3][r]));
            #pragma unroll
            for (int off = 1; off < 16; off <<= 1)
                #pragma unroll
                for (int r = 0; r < 4; ++r)
                    pmax[r] = fmaxf(pmax[r], __shfl_xor(pmax[r], off));
            #pragma unroll
            for (int r = 0; r < 4; ++r) {
                const float mnew = fmaxf(mrun[m][r], pmax[r]);
                alpha[r] = exp2f(fmaxf(mrun[m][r] - mnew, NEG) * LOG2E);
                mrun[m][r] = mnew;
                float ps = 0.f;
                #pragma unroll
                for (int sf = 0; sf < 4; ++sf) {
                    const float p = exp2f(fmaxf(s[m][sf][r] - mnew, NEG) * LOG2E);
                    s[m][sf][r] = p;
                    ps += p;
                }
                psum[r] = ps;
            }
            #pragma unroll
            for (int off = 1; off < 16; off <<= 1)
                #pragma unroll
                for (int r = 0; r < 4; ++r)
                    psum[r] += __shfl_xor(psum[r], off);
            #pragma unroll
            for (int r = 0; r < 4; ++r) {
                lrun[m][r] = lrun[m][r] * alpha[r] + psum[r];
                #pragma unroll
                for (int nf = 0; nf < 4; ++nf) o[m][nf][r] *= alpha[r];
            }
            #pragma unroll
            for (int sf = 0; sf < 4; ++sf)
                #pragma unroll
                for (int r = 0; r < 4; ++r)
                    lP[wave][m * 16 + rbase + r][sf * 16 + (lane & 15)] = f2bf(s[m][sf][r]);
        }
        #pragma unroll
        for (int ks = 0; ks < 2; ++ks) {
            bf16x8 pa[2];
            #pragma unroll
            for (int m = 0; m < 2; ++m)
                pa[m] = *(const bf16x8*)&lP[wave][m * 16 + frow][ks * 32 + fk8];
            #pragma unroll
            for (int nf = 0; nf < 4; ++nf) {
                const bf16x8 vb = *(const bf16x8*)&lV[nf * 16 + frow][ks * 32 + fk8];
                #pragma unroll
                for (int m = 0; m < 2; ++m)
                    o[m][nf] = MFMA_16x16x32(pa[m], vb, o[m][nf]);
            }
        }
    }

    #pragma unroll
    for (int m = 0; m < 2; ++m) {
        float inv[4];
        #pragma unroll
        for (int r = 0; r < 4; ++r) inv[r] = 1.0f / fmaxf(lrun[m][r], 1e-30f);
        #pragma unroll
        for (int nf = 0; nf < 4; ++nf)
            #pragma unroll
            for (int r = 0; r < 4; ++r) {
                const int row = qt0 + wrow + m * 16 + rbase + r;
                const int col = nf * 16 + (lane & 15);
                O[row * 64 + col] = f2bf(o[m][nf][r] * inv[r]);
            }
    }
}

extern "C" void kernel_launch(void* const* d_in, const int* in_sizes, int n_in,
                              void* d_out, int out_size, void* d_ws, size_t ws_size,
                              hipStream_t stream) {
    const float* x  = (const float*)d_in[0];   // x_q  [4,2048,512] fp32
    const float* Wq = (const float*)d_in[1];   // [8,64,512] fp32
    const float* Wk = (const float*)d_in[2];
    const float* Wv = (const float*)d_in[3];
    const float* Wp = (const float*)d_in[4];   // [512,512] fp32
    const float* bp = (const float*)d_in[5];   // [512] fp32
    float* out = (float*)d_out;                // [4,2048,512] fp32

    const size_t NEL  = 4u * 8u * 2048u * 64u;   // 4,194,304 (all batches)
    const size_t NELB = 8u * 2048u * 64u;        // 1,048,576 (one batch)
    const float qscale = 0.04419417382415922f;   // 512^-0.5 folded into q

    if (ws_size >= 3u * NEL * sizeof(ushort)) {
        // q (bf16) lives in d_out's bytes; final GEMM overwrites d_out (fp32)
        ushort* qb = (ushort*)d_out;
        ushort* kb = (ushort*)d_ws;
        ushort* vb = kb + NEL;
        ushort* ab = vb + NEL;
        const dim3 gg(64, 4), bb(256);
        hipLaunchKernelGGL(gemm_qkv, gg, bb, 0, stream, x, Wq, qscale, qb);
        hipLaunchKernelGGL(gemm_qkv, gg, bb, 0, stream, x, Wk, 1.0f, kb);
        hipLaunchKernelGGL(gemm_qkv, gg, bb, 0, stream, x, Wv, 1.0f, vb);
        hipLaunchKernelGGL(attn_kernel, dim3(16, 32), dim3(256), 0, stream, qb, kb, vb, ab);
        hipLaunchKernelGGL(gemm_out, gg, bb, 0, stream, ab, Wp, bp, out);
    } else {
        // per-batch fallback: ws need = 3 * NELB * 2 = 6.3 MB
        ushort* kb = (ushort*)d_ws;
        ushort* vb = kb + NELB;
        ushort* ab = vb + NELB;
        const dim3 gg(16, 4), bb(256);
        for (int b = 0; b < 4; ++b) {
            const float* xb = x + (size_t)b * 2048u * 512u;
            float* ob = out + (size_t)b * 2048u * 512u;
            ushort* qb = (ushort*)ob;            // q slice then final out
            hipLaunchKernelGGL(gemm_qkv, gg, bb, 0, stream, xb, Wq, qscale, qb);
            hipLaunchKernelGGL(gemm_qkv, gg, bb, 0, stream, xb, Wk, 1.0f, kb);
            hipLaunchKernelGGL(gemm_qkv, gg, bb, 0, stream, xb, Wv, 1.0f, vb);
            hipLaunchKernelGGL(attn_kernel, dim3(16, 8), dim3(256), 0, stream, qb, kb, vb, ab);
            hipLaunchKernelGGL(gemm_out, gg, bb, 0, stream, ab, Wp, bp, ob);
        }
    }
}

// Round 4
// 170.221 us; speedup vs baseline: 1.3303x; 1.3303x over previous
//
#include <hip/hip_runtime.h>
#include <hip/hip_bf16.h>

using bf16x8 = __attribute__((ext_vector_type(8))) __bf16;
using f32x4  = __attribute__((ext_vector_type(4))) float;
using i32x4  = __attribute__((ext_vector_type(4))) int;

#define MFMA_16x16x32(a, b, c) __builtin_amdgcn_mfma_f32_16x16x32_bf16((a), (b), (c), 0, 0, 0)

__device__ __forceinline__ ushort f2bf(float f) {
    return __builtin_bit_cast(ushort, (__bf16)f);
}

// ---------------------------------------------------------------------------
// fp32 -> bf16 vectorized convert (8 elems/thread)
// ---------------------------------------------------------------------------
__global__ __launch_bounds__(256) void cvt_bf16(
    const float* __restrict__ in, ushort* __restrict__ out, int n)
{
    const int i = (blockIdx.x * 256 + threadIdx.x) * 8;
    if (i + 8 <= n) {
        const f32x4 a = *(const f32x4*)(in + i);
        const f32x4 b = *(const f32x4*)(in + i + 4);
        union { ushort u[8]; i32x4 w; } p;
        #pragma unroll
        for (int j = 0; j < 4; ++j) { p.u[j] = f2bf(a[j]); p.u[4 + j] = f2bf(b[j]); }
        *(i32x4*)(out + i) = p.w;
    }
}

// ---------------------------------------------------------------------------
// Fused QKV GEMM: C[M,512] = A[M,512](bf16) * W[512,512](fp32)^T * scale
// blockIdx.y: (y>>2) selects {Wq,Wk,Wv}; (y&3) is the 128-col n-tile.
// out -> bf16 head-interleaved [b,h,t,64]  (b local: row>>11)
// ---------------------------------------------------------------------------
__global__ __launch_bounds__(256) void gemm_qkv3(
    const ushort* __restrict__ A, const float* __restrict__ Wq,
    const float* __restrict__ Wk, const float* __restrict__ Wv,
    float qscale, ushort* __restrict__ qb, ushort* __restrict__ kb,
    ushort* __restrict__ vb)
{
    __shared__ ushort lA[128][40];
    __shared__ ushort lB[128][40];
    const int wsel = blockIdx.y >> 2;
    const int n0 = (blockIdx.y & 3) * 128;
    const float* W = (wsel == 0) ? Wq : ((wsel == 1) ? Wk : Wv);
    ushort* out = (wsel == 0) ? qb : ((wsel == 1) ? kb : vb);
    const float scale = (wsel == 0) ? qscale : 1.0f;

    const int m0 = blockIdx.x * 128;
    const int tid  = threadIdx.x;
    const int lane = tid & 63;
    const int wave = tid >> 6;
    const int wr = (wave >> 1) * 64, wc = (wave & 1) * 64;
    const int frow = lane & 15, fk = (lane >> 4) * 8;
    const int sr = tid >> 1, scc = (tid & 1) * 16;

    f32x4 acc[4][4] = {};

    for (int k0 = 0; k0 < 512; k0 += 32) {
        const ushort* pa = A + (m0 + sr) * 512 + k0 + scc;
        const i32x4 va0 = *(const i32x4*)(pa);
        const i32x4 va1 = *(const i32x4*)(pa + 8);
        const float* pb = W + (n0 + sr) * 512 + k0 + scc;
        const f32x4 b0 = *(const f32x4*)(pb);
        const f32x4 b1 = *(const f32x4*)(pb + 4);
        const f32x4 b2 = *(const f32x4*)(pb + 8);
        const f32x4 b3 = *(const f32x4*)(pb + 12);
        union { ushort u[16]; i32x4 w[2]; } pB;
        #pragma unroll
        for (int j = 0; j < 4; ++j) {
            pB.u[j]      = f2bf(b0[j]);  pB.u[4 + j]  = f2bf(b1[j]);
            pB.u[8 + j]  = f2bf(b2[j]);  pB.u[12 + j] = f2bf(b3[j]);
        }
        __syncthreads();
        *(i32x4*)&lA[sr][scc]     = va0;
        *(i32x4*)&lA[sr][scc + 8] = va1;
        *(i32x4*)&lB[sr][scc]     = pB.w[0];
        *(i32x4*)&lB[sr][scc + 8] = pB.w[1];
        __syncthreads();

        bf16x8 af[4], bg[4];
        #pragma unroll
        for (int m = 0; m < 4; ++m) af[m] = *(const bf16x8*)&lA[wr + m * 16 + frow][fk];
        #pragma unroll
        for (int n = 0; n < 4; ++n) bg[n] = *(const bf16x8*)&lB[wc + n * 16 + frow][fk];
        #pragma unroll
        for (int m = 0; m < 4; ++m)
            #pragma unroll
            for (int n = 0; n < 4; ++n)
                acc[m][n] = MFMA_16x16x32(af[m], bg[n], acc[m][n]);
    }

    const int rbase = (lane >> 4) * 4;
    const int ccol  = lane & 15;
    #pragma unroll
    for (int m = 0; m < 4; ++m)
        #pragma unroll
        for (int n = 0; n < 4; ++n) {
            const int col = n0 + wc + n * 16 + ccol;
            #pragma unroll
            for (int r = 0; r < 4; ++r) {
                const int row = m0 + wr + m * 16 + rbase + r;
                out[(((row >> 11) * 8 + (col >> 6)) * 2048 + (row & 2047)) * 64 + (col & 63)]
                    = f2bf(acc[m][n][r] * scale);
            }
        }
}

// ---------------------------------------------------------------------------
// Output GEMM: C[M,512](fp32) = A[M,512](bf16, head-interleaved) * Wp^T + bp
// ---------------------------------------------------------------------------
__global__ __launch_bounds__(256) void gemm_out(
    const ushort* __restrict__ A, const float* __restrict__ W,
    const float* __restrict__ bias, float* __restrict__ out)
{
    __shared__ ushort lA[128][40];
    __shared__ ushort lB[128][40];
    const int m0 = blockIdx.x * 128;
    const int n0 = blockIdx.y * 128;
    const int tid  = threadIdx.x;
    const int lane = tid & 63;
    const int wave = tid >> 6;
    const int wr = (wave >> 1) * 64, wc = (wave & 1) * 64;
    const int frow = lane & 15, fk = (lane >> 4) * 8;
    const int sr = tid >> 1, scc = (tid & 1) * 16;

    f32x4 acc[4][4] = {};

    for (int k0 = 0; k0 < 512; k0 += 32) {
        const int row = m0 + sr, c = k0 + scc;
        const ushort* pa = A + ((((row >> 11) * 8 + (c >> 6)) * 2048 + (row & 2047)) * 64 + (c & 63));
        const i32x4 va0 = *(const i32x4*)(pa);
        const i32x4 va1 = *(const i32x4*)(pa + 8);
        const float* pb = W + (n0 + sr) * 512 + k0 + scc;
        const f32x4 b0 = *(const f32x4*)(pb);
        const f32x4 b1 = *(const f32x4*)(pb + 4);
        const f32x4 b2 = *(const f32x4*)(pb + 8);
        const f32x4 b3 = *(const f32x4*)(pb + 12);
        union { ushort u[16]; i32x4 w[2]; } pB;
        #pragma unroll
        for (int j = 0; j < 4; ++j) {
            pB.u[j]      = f2bf(b0[j]);  pB.u[4 + j]  = f2bf(b1[j]);
            pB.u[8 + j]  = f2bf(b2[j]);  pB.u[12 + j] = f2bf(b3[j]);
        }
        __syncthreads();
        *(i32x4*)&lA[sr][scc]     = va0;
        *(i32x4*)&lA[sr][scc + 8] = va1;
        *(i32x4*)&lB[sr][scc]     = pB.w[0];
        *(i32x4*)&lB[sr][scc + 8] = pB.w[1];
        __syncthreads();

        bf16x8 af[4], bg[4];
        #pragma unroll
        for (int m = 0; m < 4; ++m) af[m] = *(const bf16x8*)&lA[wr + m * 16 + frow][fk];
        #pragma unroll
        for (int n = 0; n < 4; ++n) bg[n] = *(const bf16x8*)&lB[wc + n * 16 + frow][fk];
        #pragma unroll
        for (int m = 0; m < 4; ++m)
            #pragma unroll
            for (int n = 0; n < 4; ++n)
                acc[m][n] = MFMA_16x16x32(af[m], bg[n], acc[m][n]);
    }

    const int rbase = (lane >> 4) * 4;
    const int ccol  = lane & 15;
    #pragma unroll
    for (int m = 0; m < 4; ++m)
        #pragma unroll
        for (int n = 0; n < 4; ++n) {
            const int col = n0 + wc + n * 16 + ccol;
            const float bv = bias[col];
            #pragma unroll
            for (int r = 0; r < 4; ++r) {
                const int row = m0 + wr + m * 16 + rbase + r;
                out[row * 512 + col] = acc[m][n][r] + bv;
            }
        }
}

// ---------------------------------------------------------------------------
// Causal flash attention per (local bh): Q,K,V [2048,64] bf16 (q pre-scaled).
// Block: 128 q-rows (heavy-first remap), 4 waves x 32 rows, KV tiles of 64.
// T14 register prefetch of next K/V tile; row-sum via ones-MFMA (no psum
// shuffles); V transposed to LDS via packed b32 pair-writes.
// ---------------------------------------------------------------------------
__global__ __launch_bounds__(256) void attn_kernel(
    const ushort* __restrict__ q, const ushort* __restrict__ k,
    const ushort* __restrict__ v, ushort* __restrict__ att)
{
    __shared__ ushort lK[64][72];       // K tile row-major [s][d]
    __shared__ ushort lV[64][72];       // V tile transposed [d][s]
    __shared__ ushort lP[4][32][72];    // per-wave P round-trip

    const int bh  = blockIdx.y;
    const int qt0 = (gridDim.x - 1 - blockIdx.x) * 128;   // heavy-first
    const ushort* Q = q + bh * 2048 * 64;
    const ushort* K = k + bh * 2048 * 64;
    const ushort* V = v + bh * 2048 * 64;
    ushort* O = att + bh * 2048 * 64;

    const int tid = threadIdx.x, wave = tid >> 6, lane = tid & 63;
    const int wrow = wave * 32;
    const int frow = lane & 15, fk8 = (lane >> 4) * 8;
    const int rbase = (lane >> 4) * 4;
    const float LOG2E = 1.44269504088896f;
    const float NEG = -30000.0f;

    // staging maps
    const int ls = tid >> 2, cq = (tid & 3) * 16;     // K: row ls, col quarter
    const int sa = tid & 31, db = tid >> 5;           // V: s-pair sa, d-group db

    bf16x8 aq[2][2];
    #pragma unroll
    for (int m = 0; m < 2; ++m)
        #pragma unroll
        for (int ks = 0; ks < 2; ++ks)
            aq[m][ks] = *(const bf16x8*)(Q + (qt0 + wrow + m * 16 + frow) * 64 + ks * 32 + fk8);

    const i32x4 onesw = {0x3F803F80, 0x3F803F80, 0x3F803F80, 0x3F803F80};
    const bf16x8 ones = __builtin_bit_cast(bf16x8, onesw);

    f32x4 o[2][4] = {};
    f32x4 osum[2] = {};
    float mrun[2][4];
    #pragma unroll
    for (int m = 0; m < 2; ++m)
        #pragma unroll
        for (int r = 0; r < 4; ++r) mrun[m][r] = NEG;

    const int nt = qt0 / 64 + 2;

    // prefetch registers
    i32x4 kx0, kx1, vv0, vv1;
    auto issue = [&](int s0) {
        kx0 = *(const i32x4*)(K + (s0 + ls) * 64 + cq);
        kx1 = *(const i32x4*)(K + (s0 + ls) * 64 + cq + 8);
        vv0 = *(const i32x4*)(V + (s0 + 2 * sa) * 64 + 8 * db);
        vv1 = *(const i32x4*)(V + (s0 + 2 * sa + 1) * 64 + 8 * db);
    };
    issue(0);

    for (int t = 0; t < nt; ++t) {
        const int s0 = t * 64;
        __syncthreads();                 // prior tile's LDS reads done
        *(i32x4*)&lK[ls][cq]     = kx0;
        *(i32x4*)&lK[ls][cq + 8] = kx1;
        #pragma unroll
        for (int j = 0; j < 8; ++j) {
            const unsigned w0 = (unsigned)vv0[j >> 1];
            const unsigned w1 = (unsigned)vv1[j >> 1];
            const unsigned e0 = (j & 1) ? (w0 >> 16) : (w0 & 0xffffu);
            const unsigned e1 = (j & 1) ? (w1 >> 16) : (w1 & 0xffffu);
            *(unsigned*)&lV[8 * db + j][2 * sa] = e0 | (e1 << 16);
        }
        __syncthreads();
        if (t + 1 < nt) issue(s0 + 64);  // prefetch overlaps compute

        // S = Q K^T
        f32x4 s[2][4] = {};
        #pragma unroll
        for (int sf = 0; sf < 4; ++sf) {
            #pragma unroll
            for (int ks = 0; ks < 2; ++ks) {
                const bf16x8 kb = *(const bf16x8*)&lK[sf * 16 + frow][ks * 32 + fk8];
                #pragma unroll
                for (int m = 0; m < 2; ++m)
                    s[m][sf] = MFMA_16x16x32(aq[m][ks], kb, s[m][sf]);
            }
        }
        if (s0 + 63 > qt0 + wrow) {
            #pragma unroll
            for (int m = 0; m < 2; ++m)
                #pragma unroll
                for (int sf = 0; sf < 4; ++sf)
                    #pragma unroll
                    for (int r = 0; r < 4; ++r) {
                        const int row = qt0 + wrow + m * 16 + rbase + r;
                        const int col = s0 + sf * 16 + (lane & 15);
                        if (col > row) s[m][sf][r] = NEG;
                    }
        }
        // online softmax: max via in-lane + 16-lane shuffle; sums via ones-MFMA
        #pragma unroll
        for (int m = 0; m < 2; ++m) {
            float pmax[4], alpha[4];
            #pragma unroll
            for (int r = 0; r < 4; ++r)
                pmax[r] = fmaxf(fmaxf(s[m][0][r], s[m][1][r]), fmaxf(s[m][2][r], s[m][3][r]));
            #pragma unroll
            for (int off = 1; off < 16; off <<= 1)
                #pragma unroll
                for (int r = 0; r < 4; ++r)
                    pmax[r] = fmaxf(pmax[r], __shfl_xor(pmax[r], off));
            #pragma unroll
            for (int r = 0; r < 4; ++r) {
                const float mnew = fmaxf(mrun[m][r], pmax[r]);
                alpha[r] = exp2f(fmaxf(mrun[m][r] - mnew, NEG) * LOG2E);
                mrun[m][r] = mnew;
                #pragma unroll
                for (int sf = 0; sf < 4; ++sf)
                    s[m][sf][r] = exp2f(fmaxf(s[m][sf][r] - mnew, NEG) * LOG2E);
            }
            #pragma unroll
            for (int r = 0; r < 4; ++r) {
                osum[m][r] *= alpha[r];
                #pragma unroll
                for (int nf = 0; nf < 4; ++nf) o[m][nf][r] *= alpha[r];
            }
            #pragma unroll
            for (int sf = 0; sf < 4; ++sf)
                #pragma unroll
                for (int r = 0; r < 4; ++r)
                    lP[wave][m * 16 + rbase + r][sf * 16 + (lane & 15)] = f2bf(s[m][sf][r]);
        }
        // O += P*V ; osum += P*ones  (wave-local lP, no barrier needed)
        #pragma unroll
        for (int ks = 0; ks < 2; ++ks) {
            bf16x8 pa[2];
            #pragma unroll
            for (int m = 0; m < 2; ++m)
                pa[m] = *(const bf16x8*)&lP[wave][m * 16 + frow][ks * 32 + fk8];
            #pragma unroll
            for (int nf = 0; nf < 4; ++nf) {
                const bf16x8 vb = *(const bf16x8*)&lV[nf * 16 + frow][ks * 32 + fk8];
                #pragma unroll
                for (int m = 0; m < 2; ++m)
                    o[m][nf] = MFMA_16x16x32(pa[m], vb, o[m][nf]);
            }
            #pragma unroll
            for (int m = 0; m < 2; ++m)
                osum[m] = MFMA_16x16x32(pa[m], ones, osum[m]);
        }
    }

    #pragma unroll
    for (int m = 0; m < 2; ++m) {
        float inv[4];
        #pragma unroll
        for (int r = 0; r < 4; ++r) inv[r] = 1.0f / fmaxf(osum[m][r], 1e-30f);
        #pragma unroll
        for (int nf = 0; nf < 4; ++nf)
            #pragma unroll
            for (int r = 0; r < 4; ++r) {
                const int row = qt0 + wrow + m * 16 + rbase + r;
                const int col = nf * 16 + (lane & 15);
                O[row * 64 + col] = f2bf(o[m][nf][r] * inv[r]);
            }
    }
}

extern "C" void kernel_launch(void* const* d_in, const int* in_sizes, int n_in,
                              void* d_out, int out_size, void* d_ws, size_t ws_size,
                              hipStream_t stream) {
    const float* x  = (const float*)d_in[0];   // x_q  [4,2048,512] fp32
    const float* Wq = (const float*)d_in[1];   // [8,64,512] fp32
    const float* Wk = (const float*)d_in[2];
    const float* Wv = (const float*)d_in[3];
    const float* Wp = (const float*)d_in[4];   // [512,512] fp32
    const float* bp = (const float*)d_in[5];   // [512] fp32
    float* out = (float*)d_out;                // [4,2048,512] fp32

    const size_t NEL  = 4u * 8u * 2048u * 64u;   // 4,194,304 (all batches)
    const size_t NELB = 8u * 2048u * 64u;        // 1,048,576 (one batch)
    const float qscale = 0.04419417382415922f;   // 512^-0.5 folded into q

    if (ws_size >= 3u * NEL * sizeof(ushort)) {
        // d_out bytes: [xbf (bf16 x)][qb (bf16 q)] — final GEMM overwrites
        ushort* xbf = (ushort*)d_out;
        ushort* qb  = xbf + NEL;
        ushort* kb  = (ushort*)d_ws;
        ushort* vb  = kb + NEL;
        ushort* ab  = vb + NEL;
        hipLaunchKernelGGL(cvt_bf16, dim3((int)(NEL / (256 * 8))), dim3(256), 0, stream,
                           x, xbf, (int)NEL);
        hipLaunchKernelGGL(gemm_qkv3, dim3(64, 12), dim3(256), 0, stream,
                           xbf, Wq, Wk, Wv, qscale, qb, kb, vb);
        hipLaunchKernelGGL(attn_kernel, dim3(16, 32), dim3(256), 0, stream, qb, kb, vb, ab);
        hipLaunchKernelGGL(gemm_out, dim3(64, 4), dim3(256), 0, stream, ab, Wp, bp, out);
    } else {
        // per-batch fallback: ws need = 3 * NELB * 2 = 6.3 MB
        ushort* kb = (ushort*)d_ws;
        ushort* vb = kb + NELB;
        ushort* ab = vb + NELB;
        for (int b = 0; b < 4; ++b) {
            const float* xb = x + (size_t)b * 2048u * 512u;
            float* ob = out + (size_t)b * 2048u * 512u;
            ushort* xbf = (ushort*)ob;           // batch slice: [xbf][qb]
            ushort* qb  = xbf + NELB;
            hipLaunchKernelGGL(cvt_bf16, dim3((int)(NELB / (256 * 8))), dim3(256), 0, stream,
                               xb, xbf, (int)NELB);
            hipLaunchKernelGGL(gemm_qkv3, dim3(16, 12), dim3(256), 0, stream,
                               xbf, Wq, Wk, Wv, qscale, qb, kb, vb);
            hipLaunchKernelGGL(attn_kernel, dim3(16, 8), dim3(256), 0, stream, qb, kb, vb, ab);
            hipLaunchKernelGGL(gemm_out, dim3(16, 4), dim3(256), 0, stream, ab, Wp, bp, ob);
        }
    }
}